// Round 1
// baseline (1119.699 us; speedup 1.0000x reference)
//
#include <hip/hip_runtime.h>
#include <math.h>

#define BATCH 2
#define SEQ   2048
#define DIN   1024
#define NH    16
#define DE    64
#define MROWS (BATCH * SEQ)

// ---------------------------------------------------------------------------
// Kernel 1: QKV projection.
// C[m, h*64+e] = sum_d x[m,d] * W[h,d,e] + bias[h,e]
// grid = (MROWS/64, NH, 3{q,k,v}), block = 256 (16x16 threads, 4x4 per thread)
// ---------------------------------------------------------------------------
__global__ __launch_bounds__(256)
void qkv_proj_kernel(const float* __restrict__ x,
                     const float* __restrict__ Wq, const float* __restrict__ bq,
                     const float* __restrict__ Wk, const float* __restrict__ bk,
                     const float* __restrict__ Wv, const float* __restrict__ bv,
                     float* __restrict__ Qo, float* __restrict__ Ko,
                     float* __restrict__ Vo)
{
    const int mt = blockIdx.x;
    const int h  = blockIdx.y;
    const int z  = blockIdx.z;
    const float* __restrict__ W    = (z == 0) ? Wq : (z == 1) ? Wk : Wv;
    const float* __restrict__ bias = (z == 0) ? bq : (z == 1) ? bk : bv;
    float* __restrict__ Out        = (z == 0) ? Qo : (z == 1) ? Ko : Vo;

    __shared__ float Xs[64][17];   // [row][k], KB=16, pad->17 (stride 68 mod 32 = 4)
    __shared__ float Ws[16][68];   // [k][e]

    const int tid = threadIdx.x;
    const int ty  = tid >> 4;      // 0..15 -> rows 4ty..4ty+3
    const int tx  = tid & 15;      // 0..15 -> cols 4tx..4tx+3
    const int row0 = mt * 64;

    float acc[4][4] = {};

    for (int k0 = 0; k0 < DIN; k0 += 16) {
        // stage X tile 64x16 (256 float4 loads)
        {
            const int r  = tid >> 2;
            const int kg = (tid & 3) << 2;
            const float4 v = *reinterpret_cast<const float4*>(
                &x[(size_t)(row0 + r) * DIN + k0 + kg]);
            Xs[r][kg + 0] = v.x; Xs[r][kg + 1] = v.y;
            Xs[r][kg + 2] = v.z; Xs[r][kg + 3] = v.w;
        }
        // stage W tile 16x64 (W[h][k][e] rows contiguous)
        {
            const int kk = tid >> 4;
            const int eg = (tid & 15) << 2;
            const float4 v = *reinterpret_cast<const float4*>(
                &W[(size_t)(h * DIN + k0 + kk) * DE + eg]);
            Ws[kk][eg + 0] = v.x; Ws[kk][eg + 1] = v.y;
            Ws[kk][eg + 2] = v.z; Ws[kk][eg + 3] = v.w;
        }
        __syncthreads();
        #pragma unroll
        for (int kk = 0; kk < 16; ++kk) {
            float a[4], b[4];
            #pragma unroll
            for (int i = 0; i < 4; ++i) a[i] = Xs[4 * ty + i][kk];
            #pragma unroll
            for (int j = 0; j < 4; ++j) b[j] = Ws[kk][4 * tx + j];
            #pragma unroll
            for (int i = 0; i < 4; ++i)
                #pragma unroll
                for (int j = 0; j < 4; ++j)
                    acc[i][j] = fmaf(a[i], b[j], acc[i][j]);
        }
        __syncthreads();
    }

    float bb[4];
    #pragma unroll
    for (int j = 0; j < 4; ++j) bb[j] = bias[h * DE + 4 * tx + j];

    #pragma unroll
    for (int i = 0; i < 4; ++i) {
        const int m = row0 + 4 * ty + i;
        const int b = m >> 11;            // m / SEQ
        const int s = m & (SEQ - 1);      // m % SEQ
        float4 v;
        v.x = acc[i][0] + bb[0];
        v.y = acc[i][1] + bb[1];
        v.z = acc[i][2] + bb[2];
        v.w = acc[i][3] + bb[3];
        *reinterpret_cast<float4*>(
            &Out[(size_t)((b * NH + h) * SEQ + s) * DE + 4 * tx]) = v;
    }
}

// ---------------------------------------------------------------------------
// Kernel 2: flash attention, fp32.
// grid = (SEQ/64, NH, BATCH), block = 256. Each block: 64 query rows.
// K/V tiles of 64 staged in LDS; online softmax; P moved via wave shuffles.
// ---------------------------------------------------------------------------
__global__ __launch_bounds__(256)
void attn_kernel(const float* __restrict__ Q, const float* __restrict__ K,
                 const float* __restrict__ V, float* __restrict__ out)
{
    __shared__ float Qs[64][65];   // scalar reads, stride 260 mod 32 = 4 (conflict-free)
    __shared__ float Ks[64][65];
    __shared__ float Vs[64][68];   // float4 reads, 16B aligned, 2-way (free)

    const int tid = threadIdx.x;
    const int ty  = tid >> 4;      // rows 4ty..4ty+3
    const int tx  = tid & 15;      // keys/dims 4tx..4tx+3
    const int rb = blockIdx.x, h = blockIdx.y, b = blockIdx.z;

    const float* __restrict__ Qp = Q + (size_t)((b * NH + h) * SEQ + rb * 64) * DE;
    const float* __restrict__ Kp = K + (size_t)((b * NH + h) * SEQ) * DE;
    const float* __restrict__ Vp = V + (size_t)((b * NH + h) * SEQ) * DE;

    // stage Q tile 64x64
    #pragma unroll
    for (int u = 0; u < 4; ++u) {
        const int idx = tid + u * 256;
        const int r   = idx >> 4;
        const int eg  = (idx & 15) << 2;
        const float4 v = *reinterpret_cast<const float4*>(&Qp[r * DE + eg]);
        Qs[r][eg + 0] = v.x; Qs[r][eg + 1] = v.y;
        Qs[r][eg + 2] = v.z; Qs[r][eg + 3] = v.w;
    }

    float O[4][4] = {};
    float m_[4], l_[4];
    #pragma unroll
    for (int i = 0; i < 4; ++i) { m_[i] = -1e30f; l_[i] = 0.f; }

    for (int t0 = 0; t0 < SEQ; t0 += 64) {
        __syncthreads();   // previous tile's PV readers done before overwrite
        #pragma unroll
        for (int u = 0; u < 4; ++u) {
            const int idx = tid + u * 256;
            const int r   = idx >> 4;
            const int eg  = (idx & 15) << 2;
            const float4 kv = *reinterpret_cast<const float4*>(
                &Kp[(size_t)(t0 + r) * DE + eg]);
            Ks[r][eg + 0] = kv.x; Ks[r][eg + 1] = kv.y;
            Ks[r][eg + 2] = kv.z; Ks[r][eg + 3] = kv.w;
            const float4 vv = *reinterpret_cast<const float4*>(
                &Vp[(size_t)(t0 + r) * DE + eg]);
            *reinterpret_cast<float4*>(&Vs[r][eg]) = vv;
        }
        __syncthreads();

        // scores: sc[i][j] = Q[4ty+i] . K[4tx+j]
        float sc[4][4] = {};
        for (int k = 0; k < DE; ++k) {
            float a[4], kb[4];
            #pragma unroll
            for (int i = 0; i < 4; ++i) a[i] = Qs[4 * ty + i][k];
            #pragma unroll
            for (int j = 0; j < 4; ++j) kb[j] = Ks[4 * tx + j][k];
            #pragma unroll
            for (int i = 0; i < 4; ++i)
                #pragma unroll
                for (int j = 0; j < 4; ++j)
                    sc[i][j] = fmaf(a[i], kb[j], sc[i][j]);
        }

        // online softmax (per row; the 16 tx lanes of a ty group share rows)
        #pragma unroll
        for (int i = 0; i < 4; ++i) {
            float rm = fmaxf(fmaxf(sc[i][0], sc[i][1]), fmaxf(sc[i][2], sc[i][3]));
            rm = fmaxf(rm, __shfl_xor(rm, 1));
            rm = fmaxf(rm, __shfl_xor(rm, 2));
            rm = fmaxf(rm, __shfl_xor(rm, 4));
            rm = fmaxf(rm, __shfl_xor(rm, 8));
            const float mn    = fmaxf(m_[i], rm);
            const float scale = __expf(m_[i] - mn);
            float rs = 0.f;
            #pragma unroll
            for (int j = 0; j < 4; ++j) {
                sc[i][j] = __expf(sc[i][j] - mn);
                rs += sc[i][j];
            }
            rs += __shfl_xor(rs, 1);
            rs += __shfl_xor(rs, 2);
            rs += __shfl_xor(rs, 4);
            rs += __shfl_xor(rs, 8);
            l_[i] = l_[i] * scale + rs;
            m_[i] = mn;
            #pragma unroll
            for (int j = 0; j < 4; ++j) O[i][j] *= scale;
        }

        // PV: O[i][j] += P[4ty+i][c] * V[c][4tx+j]; P gathered via shuffles
        const int laneBase = (ty & 3) << 4;
        for (int cg = 0; cg < 16; ++cg) {
            const int srcLane = laneBase + cg;
            #pragma unroll
            for (int jj = 0; jj < 4; ++jj) {
                const int c = (cg << 2) + jj;
                const float p0 = __shfl(sc[0][jj], srcLane, 64);
                const float p1 = __shfl(sc[1][jj], srcLane, 64);
                const float p2 = __shfl(sc[2][jj], srcLane, 64);
                const float p3 = __shfl(sc[3][jj], srcLane, 64);
                const float4 vv = *reinterpret_cast<const float4*>(&Vs[c][4 * tx]);
                O[0][0] = fmaf(p0, vv.x, O[0][0]);
                O[0][1] = fmaf(p0, vv.y, O[0][1]);
                O[0][2] = fmaf(p0, vv.z, O[0][2]);
                O[0][3] = fmaf(p0, vv.w, O[0][3]);
                O[1][0] = fmaf(p1, vv.x, O[1][0]);
                O[1][1] = fmaf(p1, vv.y, O[1][1]);
                O[1][2] = fmaf(p1, vv.z, O[1][2]);
                O[1][3] = fmaf(p1, vv.w, O[1][3]);
                O[2][0] = fmaf(p2, vv.x, O[2][0]);
                O[2][1] = fmaf(p2, vv.y, O[2][1]);
                O[2][2] = fmaf(p2, vv.z, O[2][2]);
                O[2][3] = fmaf(p2, vv.w, O[2][3]);
                O[3][0] = fmaf(p3, vv.x, O[3][0]);
                O[3][1] = fmaf(p3, vv.y, O[3][1]);
                O[3][2] = fmaf(p3, vv.z, O[3][2]);
                O[3][3] = fmaf(p3, vv.w, O[3][3]);
            }
        }
    }

    // epilogue: out[b][s][h*64+e] = O / (l * sqrt(64))
    #pragma unroll
    for (int i = 0; i < 4; ++i) {
        const float invl = 0.125f / l_[i];
        const int srow = rb * 64 + 4 * ty + i;
        float4 v;
        v.x = O[i][0] * invl;
        v.y = O[i][1] * invl;
        v.z = O[i][2] * invl;
        v.w = O[i][3] * invl;
        *reinterpret_cast<float4*>(
            &out[(size_t)(b * SEQ + srow) * (NH * DE) + h * DE + 4 * tx]) = v;
    }
}

extern "C" void kernel_launch(void* const* d_in, const int* in_sizes, int n_in,
                              void* d_out, int out_size, void* d_ws, size_t ws_size,
                              hipStream_t stream)
{
    (void)in_sizes; (void)n_in; (void)out_size; (void)ws_size;
    const float* x  = (const float*)d_in[0];
    const float* Wq = (const float*)d_in[1];
    const float* bq = (const float*)d_in[2];
    const float* Wk = (const float*)d_in[3];
    const float* bk = (const float*)d_in[4];
    const float* Wv = (const float*)d_in[5];
    const float* bv = (const float*)d_in[6];
    float* out = (float*)d_out;

    const size_t per = (size_t)BATCH * NH * SEQ * DE;   // 4 Mi elements = 16 MB
    float* Qw = (float*)d_ws;
    float* Kw = Qw + per;
    float* Vw = Kw + per;                               // total 48 MB of d_ws

    dim3 gp(MROWS / 64, NH, 3);
    qkv_proj_kernel<<<gp, 256, 0, stream>>>(x, Wq, bq, Wk, bk, Wv, bv, Qw, Kw, Vw);

    dim3 ga(SEQ / 64, NH, BATCH);
    attn_kernel<<<ga, 256, 0, stream>>>(Qw, Kw, Vw, out);
}

// Round 2
// 231.165 us; speedup vs baseline: 4.8437x; 4.8437x over previous
//
#include <hip/hip_runtime.h>
#include <math.h>

#define BATCH 2
#define SEQ   2048
#define DIN   1024
#define NH    16
#define DE    64
#define NTOT  3072   // 3 * 16 * 64 output columns of the fused QKV GEMM

typedef __attribute__((ext_vector_type(8))) short short8;
typedef __attribute__((ext_vector_type(4))) float f32x4;

static __device__ __forceinline__ unsigned short f2bf(float f) {
    union { float f; unsigned int u; } x; x.f = f;
    unsigned int r = x.u + 0x7fffu + ((x.u >> 16) & 1u);   // RNE
    return (unsigned short)(r >> 16);
}
static __device__ __forceinline__ float bf2f(unsigned short h) {
    union { unsigned int u; float f; } x; x.u = ((unsigned int)h) << 16;
    return x.f;
}
static __device__ __forceinline__ f32x4 mfma16(short8 a, short8 b, f32x4 c) {
    return __builtin_amdgcn_mfma_f32_16x16x32_bf16(a, b, c, 0, 0, 0);
}

// ---------------------------------------------------------------------------
// Kernel 0: W transpose + bf16 hi/lo split.
// Wt_hi/Wt_lo[n][d], n = z*1024 + h*64 + e  (row-major, K-contiguous for MFMA).
// grid = (16 d-tiles, 16 heads, 3 z), block = 256.
// ---------------------------------------------------------------------------
__global__ __launch_bounds__(256)
void wsplit_kernel(const float* __restrict__ Wq, const float* __restrict__ Wk,
                   const float* __restrict__ Wv,
                   unsigned short* __restrict__ Wt_hi,
                   unsigned short* __restrict__ Wt_lo)
{
    const int dt = blockIdx.x, h = blockIdx.y, z = blockIdx.z;
    const float* __restrict__ W = (z == 0) ? Wq : (z == 1) ? Wk : Wv;
    __shared__ float Ws[64][65];
    const int t = threadIdx.x;
    const int d0 = dt * 64;
    #pragma unroll
    for (int u = 0; u < 4; ++u) {
        int id = t + 256 * u;
        int d = id >> 4, e0 = (id & 15) * 4;
        float4 v = *reinterpret_cast<const float4*>(&W[(size_t)(h * DIN + d0 + d) * DE + e0]);
        Ws[d][e0] = v.x; Ws[d][e0 + 1] = v.y; Ws[d][e0 + 2] = v.z; Ws[d][e0 + 3] = v.w;
    }
    __syncthreads();
    #pragma unroll
    for (int u = 0; u < 2; ++u) {
        int id = t + 256 * u;
        int e = id >> 3, dc = (id & 7) * 8;
        short8 sh, sl;
        #pragma unroll
        for (int j = 0; j < 8; ++j) {
            float v = Ws[dc + j][e];
            unsigned short hh = f2bf(v);
            sh[j] = (short)hh;
            sl[j] = (short)f2bf(v - bf2f(hh));
        }
        int n = z * 1024 + h * 64 + e;
        size_t off = (size_t)n * DIN + d0 + dc;
        *reinterpret_cast<short8*>(&Wt_hi[off]) = sh;
        *reinterpret_cast<short8*>(&Wt_lo[off]) = sl;
    }
}

// ---------------------------------------------------------------------------
// Kernel 1: fused QKV projection, split-bf16 MFMA GEMM.
// C[m][n] = sum_k x[m][k] * Wt[n][k] + bias;  M=4096, N=3072, K=1024.
// Tile 128x128x32, 4 waves, each wave -> 64x64 via 4x4 MFMA 16x16x32 frags.
// Outputs Q,K as bf16 hi/lo and V as bf16 into d_ws ([b][h][s][e]).
// ---------------------------------------------------------------------------
__global__ __launch_bounds__(256)
void qkv_proj_kernel(const float* __restrict__ x,
                     const unsigned short* __restrict__ Wt_hi,
                     const unsigned short* __restrict__ Wt_lo,
                     const float* __restrict__ bq, const float* __restrict__ bk,
                     const float* __restrict__ bv,
                     unsigned short* __restrict__ Qhi, unsigned short* __restrict__ Qlo,
                     unsigned short* __restrict__ Khi, unsigned short* __restrict__ Klo,
                     unsigned short* __restrict__ Vb)
{
    __shared__ unsigned short As_hi[128][40], As_lo[128][40];   // [m][k], stride 80 B
    __shared__ unsigned short Bs_hi[128][40], Bs_lo[128][40];   // [n][k]

    const int t = threadIdx.x;
    const int w = t >> 6, l = t & 63, g = l >> 4, li = l & 15;
    const int wr = w >> 1, wc = w & 1;
    const int m0 = blockIdx.x * 128;
    const int n0 = blockIdx.y * 128;
    const int z  = n0 >> 10;                       // uniform per block (128 | 1024)

    const f32x4 zero4 = {0.f, 0.f, 0.f, 0.f};
    f32x4 acc[4][4];
    #pragma unroll
    for (int i = 0; i < 4; ++i)
        #pragma unroll
        for (int j = 0; j < 4; ++j) acc[i][j] = zero4;

    for (int k0 = 0; k0 < DIN; k0 += 32) {
        __syncthreads();
        // stage A (x fp32 -> hi/lo bf16): 128x32, 2 units of 8 per thread
        #pragma unroll
        for (int u = 0; u < 2; ++u) {
            int id = t + 256 * u;
            int r = id >> 2, c0 = (id & 3) * 8;
            const float* src = &x[(size_t)(m0 + r) * DIN + k0 + c0];
            float4 v0 = *reinterpret_cast<const float4*>(src);
            float4 v1 = *reinterpret_cast<const float4*>(src + 4);
            float vv[8] = {v0.x, v0.y, v0.z, v0.w, v1.x, v1.y, v1.z, v1.w};
            short8 sh, sl;
            #pragma unroll
            for (int j = 0; j < 8; ++j) {
                unsigned short hh = f2bf(vv[j]);
                sh[j] = (short)hh;
                sl[j] = (short)f2bf(vv[j] - bf2f(hh));
            }
            *reinterpret_cast<short8*>(&As_hi[r][c0]) = sh;
            *reinterpret_cast<short8*>(&As_lo[r][c0]) = sl;
        }
        // stage B (pre-split bf16, plain copy)
        #pragma unroll
        for (int u = 0; u < 2; ++u) {
            int id = t + 256 * u;
            int nl = id >> 2, c0 = (id & 3) * 8;
            size_t off = (size_t)(n0 + nl) * DIN + k0 + c0;
            *reinterpret_cast<short8*>(&Bs_hi[nl][c0]) =
                *reinterpret_cast<const short8*>(&Wt_hi[off]);
            *reinterpret_cast<short8*>(&Bs_lo[nl][c0]) =
                *reinterpret_cast<const short8*>(&Wt_lo[off]);
        }
        __syncthreads();

        short8 ah[4], al[4], bh[4], bl[4];
        #pragma unroll
        for (int mf = 0; mf < 4; ++mf) {
            ah[mf] = *reinterpret_cast<const short8*>(&As_hi[64 * wr + 16 * mf + li][8 * g]);
            al[mf] = *reinterpret_cast<const short8*>(&As_lo[64 * wr + 16 * mf + li][8 * g]);
        }
        #pragma unroll
        for (int nf = 0; nf < 4; ++nf) {
            bh[nf] = *reinterpret_cast<const short8*>(&Bs_hi[64 * wc + 16 * nf + li][8 * g]);
            bl[nf] = *reinterpret_cast<const short8*>(&Bs_lo[64 * wc + 16 * nf + li][8 * g]);
        }
        #pragma unroll
        for (int mf = 0; mf < 4; ++mf)
            #pragma unroll
            for (int nf = 0; nf < 4; ++nf) {
                acc[mf][nf] = mfma16(ah[mf], bh[nf], acc[mf][nf]);
                acc[mf][nf] = mfma16(ah[mf], bl[nf], acc[mf][nf]);
                acc[mf][nf] = mfma16(al[mf], bh[nf], acc[mf][nf]);
            }
    }

    const float* __restrict__ bias = (z == 0) ? bq : (z == 1) ? bk : bv;
    #pragma unroll
    for (int nf = 0; nf < 4; ++nf) {
        int n = n0 + 64 * wc + 16 * nf + li;
        float bv_ = bias[n & 1023];
        int hh = (n >> 6) & 15, e = n & 63;
        #pragma unroll
        for (int mf = 0; mf < 4; ++mf)
            #pragma unroll
            for (int r = 0; r < 4; ++r) {
                int m = m0 + 64 * wr + 16 * mf + 4 * g + r;
                int bat = m >> 11, s = m & 2047;
                float v = acc[mf][nf][r] + bv_;
                size_t idx = ((size_t)(bat * NH + hh) * SEQ + s) * DE + e;
                unsigned short hi = f2bf(v);
                if (z == 0) { Qhi[idx] = hi; Qlo[idx] = f2bf(v - bf2f(hi)); }
                else if (z == 1) { Khi[idx] = hi; Klo[idx] = f2bf(v - bf2f(hi)); }
                else { Vb[idx] = hi; }
            }
    }
}

// ---------------------------------------------------------------------------
// Kernel 2: flash attention via MFMA.
// S^T = mfma(K, Q^T) (split 3-term); softmax lane-local (rows = keys in regs);
// O^T = mfma(V^T, P^T), P^T built in-register via packed-bf16 shuffles.
// grid = (16 q-tiles of 128, 16 heads, 2 batch), block = 256 (4 waves x 32 q).
// ---------------------------------------------------------------------------
__global__ __launch_bounds__(256)
void attn_kernel(const unsigned short* __restrict__ Qhi_g,
                 const unsigned short* __restrict__ Qlo_g,
                 const unsigned short* __restrict__ Khi_g,
                 const unsigned short* __restrict__ Klo_g,
                 const unsigned short* __restrict__ Vb_g,
                 float* __restrict__ out)
{
    __shared__ unsigned short Kh[64][72], Kl[64][72];   // [key][d], stride 144 B
    __shared__ unsigned short Vt[64][72];               // [vdim][key]

    const int t = threadIdx.x;
    const int w = t >> 6, l = t & 63, g = l >> 4, li = l & 15;
    const int qt = blockIdx.x, h = blockIdx.y, bat = blockIdx.z;
    const size_t bh = (size_t)(bat * NH + h) * SEQ;

    // ---- prologue: hoist this wave's Q fragments (B-operand layout) ----
    short8 qh[2][2], ql[2][2];    // [cb][ks]
    #pragma unroll
    for (int ro = 0; ro < 2; ++ro) {
        __syncthreads();
        #pragma unroll
        for (int u = 0; u < 2; ++u) {
            int id = t + 256 * u;
            int r = id >> 3, c0 = (id & 7) * 8;
            size_t off = (bh + qt * 128 + ro * 64 + r) * DE + c0;
            *reinterpret_cast<short8*>(&Kh[r][c0]) =
                *reinterpret_cast<const short8*>(&Qhi_g[off]);
            *reinterpret_cast<short8*>(&Kl[r][c0]) =
                *reinterpret_cast<const short8*>(&Qlo_g[off]);
        }
        __syncthreads();
        if ((w >> 1) == ro) {
            int rq = 32 * (w & 1);
            #pragma unroll
            for (int cb = 0; cb < 2; ++cb)
                #pragma unroll
                for (int ks = 0; ks < 2; ++ks) {
                    qh[cb][ks] = *reinterpret_cast<const short8*>(&Kh[rq + 16 * cb + li][32 * ks + 8 * g]);
                    ql[cb][ks] = *reinterpret_cast<const short8*>(&Kl[rq + 16 * cb + li][32 * ks + 8 * g]);
                }
        }
    }

    const f32x4 zero4 = {0.f, 0.f, 0.f, 0.f};
    f32x4 accO[4][2];             // [vb][cb]; col = q (lane-fixed), rows = vdim
    #pragma unroll
    for (int vb = 0; vb < 4; ++vb) { accO[vb][0] = zero4; accO[vb][1] = zero4; }
    float m_c[2] = {-1e30f, -1e30f}, l_c[2] = {0.f, 0.f};

    for (int kt = 0; kt < SEQ / 64; ++kt) {
        __syncthreads();   // previous tile's LDS readers done
        // stage K hi/lo (row-major bf16 copy)
        #pragma unroll
        for (int u = 0; u < 2; ++u) {
            int id = t + 256 * u;
            int r = id >> 3, c0 = (id & 7) * 8;
            size_t off = (bh + kt * 64 + r) * DE + c0;
            *reinterpret_cast<short8*>(&Kh[r][c0]) =
                *reinterpret_cast<const short8*>(&Khi_g[off]);
            *reinterpret_cast<short8*>(&Kl[r][c0]) =
                *reinterpret_cast<const short8*>(&Klo_g[off]);
        }
        // stage V transposed: Vt[d][key]
        #pragma unroll
        for (int u = 0; u < 2; ++u) {
            int id = t + 256 * u;
            int key = id & 63, d0 = (id >> 6) * 8;
            short8 v = *reinterpret_cast<const short8*>(&Vb_g[(bh + kt * 64 + key) * DE + d0]);
            #pragma unroll
            for (int j = 0; j < 8; ++j) Vt[d0 + j][key] = (unsigned short)v[j];
        }
        __syncthreads();

        // ---- QK^T: S^T[key][q], 3-term split ----
        f32x4 st[4][2];
        #pragma unroll
        for (int rb = 0; rb < 4; ++rb) { st[rb][0] = zero4; st[rb][1] = zero4; }
        #pragma unroll
        for (int ks = 0; ks < 2; ++ks) {
            short8 kh[4], kl[4];
            #pragma unroll
            for (int rb = 0; rb < 4; ++rb) {
                kh[rb] = *reinterpret_cast<const short8*>(&Kh[16 * rb + li][32 * ks + 8 * g]);
                kl[rb] = *reinterpret_cast<const short8*>(&Kl[16 * rb + li][32 * ks + 8 * g]);
            }
            #pragma unroll
            for (int rb = 0; rb < 4; ++rb)
                #pragma unroll
                for (int cb = 0; cb < 2; ++cb) {
                    st[rb][cb] = mfma16(kh[rb], qh[cb][ks], st[rb][cb]);
                    st[rb][cb] = mfma16(kh[rb], ql[cb][ks], st[rb][cb]);
                    st[rb][cb] = mfma16(kl[rb], qh[cb][ks], st[rb][cb]);
                }
        }

        // ---- online softmax (rows=keys are lane-local; 2 shuffles per q) ----
        int ppk[4][2][2];   // packed bf16 P: [rb][cb][reg-pair]
        #pragma unroll
        for (int cb = 0; cb < 2; ++cb) {
            float mx = st[0][cb][0];
            #pragma unroll
            for (int rb = 0; rb < 4; ++rb)
                #pragma unroll
                for (int r = 0; r < 4; ++r) mx = fmaxf(mx, st[rb][cb][r]);
            mx = fmaxf(mx, __shfl_xor(mx, 16));
            mx = fmaxf(mx, __shfl_xor(mx, 32));
            float mn = fmaxf(m_c[cb], mx);
            float scl = __expf(m_c[cb] - mn);
            float rs = 0.f;
            #pragma unroll
            for (int rb = 0; rb < 4; ++rb) {
                float p0 = __expf(st[rb][cb][0] - mn);
                float p1 = __expf(st[rb][cb][1] - mn);
                float p2 = __expf(st[rb][cb][2] - mn);
                float p3 = __expf(st[rb][cb][3] - mn);
                rs += (p0 + p1) + (p2 + p3);
                ppk[rb][cb][0] = (int)f2bf(p0) | ((int)f2bf(p1) << 16);
                ppk[rb][cb][1] = (int)f2bf(p2) | ((int)f2bf(p3) << 16);
            }
            rs += __shfl_xor(rs, 16);
            rs += __shfl_xor(rs, 32);
            l_c[cb] = l_c[cb] * scl + rs;
            m_c[cb] = mn;
            #pragma unroll
            for (int vb = 0; vb < 4; ++vb) accO[vb][cb] *= scl;
        }

        // ---- PV: O^T += V^T * P^T ----
        #pragma unroll
        for (int ks = 0; ks < 2; ++ks) {
            short8 av[4];
            #pragma unroll
            for (int vb = 0; vb < 4; ++vb)
                av[vb] = *reinterpret_cast<const short8*>(&Vt[16 * vb + li][32 * ks + 8 * g]);
            #pragma unroll
            for (int cb = 0; cb < 2; ++cb) {
                int dw[4];
                #pragma unroll
                for (int tp = 0; tp < 4; ++tp) {
                    int tt = tp & 1;
                    int sl = li + 16 * (2 * (g & 1) + (tp >> 1));
                    int y0 = __shfl(ppk[2 * ks][cb][tt], sl, 64);
                    int y1 = __shfl(ppk[2 * ks + 1][cb][tt], sl, 64);
                    dw[tp] = (g >> 1) ? y1 : y0;
                }
                union { int i[4]; short8 s; } u4;
                u4.i[0] = dw[0]; u4.i[1] = dw[1]; u4.i[2] = dw[2]; u4.i[3] = dw[3];
                #pragma unroll
                for (int vb = 0; vb < 4; ++vb)
                    accO[vb][cb] = mfma16(av[vb], u4.s, accO[vb][cb]);
            }
        }
    }

    // ---- epilogue: out[b][s][h*64+vd] = O^T / (l * 8) ----
    #pragma unroll
    for (int cb = 0; cb < 2; ++cb) {
        float invl = 0.125f / l_c[cb];
        int s = qt * 128 + 32 * w + 16 * cb + li;
        #pragma unroll
        for (int vb = 0; vb < 4; ++vb) {
            float4 o;
            o.x = accO[vb][cb][0] * invl;
            o.y = accO[vb][cb][1] * invl;
            o.z = accO[vb][cb][2] * invl;
            o.w = accO[vb][cb][3] * invl;
            int vd = 16 * vb + 4 * g;
            *reinterpret_cast<float4*>(&out[((size_t)bat * SEQ + s) * 1024 + h * 64 + vd]) = o;
        }
    }
}

extern "C" void kernel_launch(void* const* d_in, const int* in_sizes, int n_in,
                              void* d_out, int out_size, void* d_ws, size_t ws_size,
                              hipStream_t stream)
{
    (void)in_sizes; (void)n_in; (void)out_size; (void)ws_size;
    const float* x  = (const float*)d_in[0];
    const float* Wq = (const float*)d_in[1];
    const float* bq = (const float*)d_in[2];
    const float* Wk = (const float*)d_in[3];
    const float* bk = (const float*)d_in[4];
    const float* Wv = (const float*)d_in[5];
    const float* bv = (const float*)d_in[6];
    float* out = (float*)d_out;

    // Stage-1 scratch inside d_out (12.6 MB <= 16.8 MB); dead before attn writes.
    unsigned short* Wt_hi = (unsigned short*)d_out;
    unsigned short* Wt_lo = Wt_hi + (size_t)NTOT * DIN;

    // d_ws: Qhi,Qlo,Khi,Klo,Vb bf16 [B][H][S][64]  (5 x 8 MB = 42 MB)
    const size_t per = (size_t)BATCH * NH * SEQ * DE;
    unsigned short* ws = (unsigned short*)d_ws;
    unsigned short* Qhi = ws;
    unsigned short* Qlo = Qhi + per;
    unsigned short* Khi = Qlo + per;
    unsigned short* Klo = Khi + per;
    unsigned short* Vb  = Klo + per;

    wsplit_kernel<<<dim3(16, NH, 3), 256, 0, stream>>>(Wq, Wk, Wv, Wt_hi, Wt_lo);
    qkv_proj_kernel<<<dim3(32, 24), 256, 0, stream>>>(x, Wt_hi, Wt_lo, bq, bk, bv,
                                                      Qhi, Qlo, Khi, Klo, Vb);
    attn_kernel<<<dim3(16, NH, BATCH), 256, 0, stream>>>(Qhi, Qlo, Khi, Klo, Vb, out);
}

// Round 3
// 191.347 us; speedup vs baseline: 5.8517x; 1.2081x over previous
//
#include <hip/hip_runtime.h>

#define BATCH 2
#define SEQ   2048
#define DIN   1024
#define NH    16
#define DE    64

typedef __attribute__((ext_vector_type(8))) short short8;
typedef __attribute__((ext_vector_type(4))) float f32x4;
typedef __attribute__((ext_vector_type(4))) unsigned short ushort4_t;

static __device__ __forceinline__ unsigned short f2bf(float f) {
    union { float f; unsigned int u; } x; x.f = f;
    unsigned int r = x.u + 0x7fffu + ((x.u >> 16) & 1u);   // RNE
    return (unsigned short)(r >> 16);
}
static __device__ __forceinline__ float bf2f(unsigned short h) {
    union { unsigned int u; float f; } x; x.u = ((unsigned int)h) << 16;
    return x.f;
}
static __device__ __forceinline__ f32x4 mfma16(short8 a, short8 b, f32x4 c) {
    return __builtin_amdgcn_mfma_f32_16x16x32_bf16(a, b, c, 0, 0, 0);
}
// async global->LDS, 16B per lane; dest = wave-uniform base + lane*16
static __device__ __forceinline__ void gld16(unsigned short* l, const unsigned short* g) {
    __builtin_amdgcn_global_load_lds(
        (const __attribute__((address_space(1))) void*)g,
        (__attribute__((address_space(3))) void*)l, 16, 0, 0);
}
// pack two f32 -> packed bf16 (round-half-up) in one v_perm
static __device__ __forceinline__ int pkbf(float a, float b) {
    union { float f; unsigned int u; } x, y; x.f = a; y.f = b;
    return __builtin_amdgcn_perm(y.u + 0x8000u, x.u + 0x8000u, 0x07060302);
}
// swizzled b128 read from a [R][64] bf16 tile (128B rows, XOR (row&7) on 16B units)
static __device__ __forceinline__ short8 lds64(const unsigned short* buf, int row, int u) {
    return *reinterpret_cast<const short8*>(buf + row * 64 + ((u ^ (row & 7)) << 3));
}
// swizzled b128 read from a [R][32] bf16 tile (row-pair scheme, 2-way free)
static __device__ __forceinline__ short8 lds32(const unsigned short* buf, int row, int g) {
    int p = row >> 1, e = ((row & 1) << 2) | g;
    return *reinterpret_cast<const short8*>(buf + p * 64 + ((e ^ (p & 7)) << 3));
}

// ---------------------------------------------------------------------------
// Kernel A: split x (fp32) -> x_hi, x_lo (bf16). 2048 blocks x 256, 8 elem/thr.
// ---------------------------------------------------------------------------
__global__ __launch_bounds__(256)
void xsplit_kernel(const float* __restrict__ x,
                   unsigned short* __restrict__ xh, unsigned short* __restrict__ xl)
{
    size_t i0 = ((size_t)blockIdx.x * 256 + threadIdx.x) * 8;
    float4 a = *reinterpret_cast<const float4*>(&x[i0]);
    float4 b = *reinterpret_cast<const float4*>(&x[i0 + 4]);
    float vv[8] = {a.x, a.y, a.z, a.w, b.x, b.y, b.z, b.w};
    short8 sh, sl;
    #pragma unroll
    for (int j = 0; j < 8; ++j) {
        unsigned short hh = f2bf(vv[j]);
        sh[j] = (short)hh;
        sl[j] = (short)f2bf(vv[j] - bf2f(hh));
    }
    *reinterpret_cast<short8*>(&xh[i0]) = sh;
    *reinterpret_cast<short8*>(&xl[i0]) = sl;
}

// ---------------------------------------------------------------------------
// Kernel B: W transpose + bf16 hi/lo split (unchanged from R2).
// Wt rows: n = z*1024 + h*64 + e, K-contiguous.
// ---------------------------------------------------------------------------
__global__ __launch_bounds__(256)
void wsplit_kernel(const float* __restrict__ Wq, const float* __restrict__ Wk,
                   const float* __restrict__ Wv,
                   unsigned short* __restrict__ Wt_hi,
                   unsigned short* __restrict__ Wt_lo)
{
    const int dt = blockIdx.x, h = blockIdx.y, z = blockIdx.z;
    const float* __restrict__ W = (z == 0) ? Wq : (z == 1) ? Wk : Wv;
    __shared__ float Ws[64][65];
    const int t = threadIdx.x;
    const int d0 = dt * 64;
    #pragma unroll
    for (int u = 0; u < 4; ++u) {
        int id = t + 256 * u;
        int d = id >> 4, e0 = (id & 15) * 4;
        float4 v = *reinterpret_cast<const float4*>(&W[(size_t)(h * DIN + d0 + d) * DE + e0]);
        Ws[d][e0] = v.x; Ws[d][e0 + 1] = v.y; Ws[d][e0 + 2] = v.z; Ws[d][e0 + 3] = v.w;
    }
    __syncthreads();
    #pragma unroll
    for (int u = 0; u < 2; ++u) {
        int id = t + 256 * u;
        int e = id >> 3, dc = (id & 7) * 8;
        short8 sh, sl;
        #pragma unroll
        for (int j = 0; j < 8; ++j) {
            float v = Ws[dc + j][e];
            unsigned short hh = f2bf(v);
            sh[j] = (short)hh;
            sl[j] = (short)f2bf(v - bf2f(hh));
        }
        int n = z * 1024 + h * 64 + e;
        size_t off = (size_t)n * DIN + d0 + dc;
        *reinterpret_cast<short8*>(&Wt_hi[off]) = sh;
        *reinterpret_cast<short8*>(&Wt_lo[off]) = sl;
    }
}

// ---------------------------------------------------------------------------
// Kernel C: projection GEMM via gload_lds + swizzled LDS.
// PHASE 0: Q,K (3-term split, N=2048, 512 blocks)  -> Qhi/Qlo/Khi/Klo
// PHASE 1: V  (1-term hi,     N=1024, 256 blocks)  -> Vt_g [b][h][e][s]
// Tile 128x128xK32, 4 waves, 4x4 16x16x32 frags per wave.
// ---------------------------------------------------------------------------
template <int PHASE>
__global__ __launch_bounds__(256)
void proj_kernel(const unsigned short* __restrict__ xh, const unsigned short* __restrict__ xl,
                 const unsigned short* __restrict__ Wt_hi, const unsigned short* __restrict__ Wt_lo,
                 const float* __restrict__ bq, const float* __restrict__ bk,
                 const float* __restrict__ bv,
                 unsigned short* __restrict__ Qhi, unsigned short* __restrict__ Qlo,
                 unsigned short* __restrict__ Khi, unsigned short* __restrict__ Klo,
                 unsigned short* __restrict__ Vt_g)
{
    __shared__ __attribute__((aligned(16))) unsigned short As_h[128 * 32];
    __shared__ __attribute__((aligned(16))) unsigned short Bs_h[128 * 32];
    __shared__ __attribute__((aligned(16))) unsigned short As_l[PHASE == 0 ? 128 * 32 : 8];
    __shared__ __attribute__((aligned(16))) unsigned short Bs_l[PHASE == 0 ? 128 * 32 : 8];

    const int t = threadIdx.x;
    const int w = t >> 6, lane = t & 63, g = lane >> 4, li = lane & 15;
    const int wr = w >> 1, wc = w & 1;

    // XCD-aware bijective swizzle (grid % 8 == 0)
    const int bid = blockIdx.x;
    const int per = (PHASE == 0 ? 512 : 256) >> 3;
    const int gix = (bid & 7) * per + (bid >> 3);
    int mt, nt;
    if (PHASE == 0) { nt = gix & 15; mt = gix >> 4; }
    else            { nt = gix & 7;  mt = gix >> 3; }
    const int m0 = mt * 128, n0 = nt * 128;
    const int wrow = (PHASE == 0 ? 0 : 2048) + n0;

    const f32x4 zero4 = {0.f, 0.f, 0.f, 0.f};
    f32x4 acc[4][4];
    #pragma unroll
    for (int i = 0; i < 4; ++i)
        #pragma unroll
        for (int j = 0; j < 4; ++j) acc[i][j] = zero4;

    for (int k0 = 0; k0 < DIN; k0 += 32) {
        __syncthreads();
        #pragma unroll
        for (int rnd = 0; rnd < 2; ++rnd) {
            // linear unit U -> (row-pair swizzled) logical source
            const int U = rnd * 256 + t;
            const int p = U >> 3, i = U & 7, e = i ^ (p & 7);
            const int r = 2 * p + (e >> 2), c = (e & 3) * 8;
            const int ldso = (rnd * 256 + w * 64) * 8;   // wave-uniform base (bf16 elems)
            const size_t aoff = (size_t)(m0 + r) * DIN + k0 + c;
            const size_t boff = (size_t)(wrow + r) * DIN + k0 + c;
            gld16(As_h + ldso, xh + aoff);
            gld16(Bs_h + ldso, Wt_hi + boff);
            if constexpr (PHASE == 0) {
                gld16(As_l + ldso, xl + aoff);
                gld16(Bs_l + ldso, Wt_lo + boff);
            }
        }
        __syncthreads();

        short8 ah[4], bh[4], al[4], bl[4];
        #pragma unroll
        for (int mf = 0; mf < 4; ++mf) ah[mf] = lds32(As_h, 64 * wr + 16 * mf + li, g);
        #pragma unroll
        for (int nf = 0; nf < 4; ++nf) bh[nf] = lds32(Bs_h, 64 * wc + 16 * nf + li, g);
        if constexpr (PHASE == 0) {
            #pragma unroll
            for (int mf = 0; mf < 4; ++mf) al[mf] = lds32(As_l, 64 * wr + 16 * mf + li, g);
            #pragma unroll
            for (int nf = 0; nf < 4; ++nf) bl[nf] = lds32(Bs_l, 64 * wc + 16 * nf + li, g);
        }
        #pragma unroll
        for (int mf = 0; mf < 4; ++mf)
            #pragma unroll
            for (int nf = 0; nf < 4; ++nf) {
                acc[mf][nf] = mfma16(ah[mf], bh[nf], acc[mf][nf]);
                if constexpr (PHASE == 0) {
                    acc[mf][nf] = mfma16(ah[mf], bl[nf], acc[mf][nf]);
                    acc[mf][nf] = mfma16(al[mf], bh[nf], acc[mf][nf]);
                }
            }
    }

    if constexpr (PHASE == 0) {
        const float* __restrict__ bias = (nt < 8) ? bq : bk;
        unsigned short* __restrict__ Dh = (nt < 8) ? Qhi : Khi;
        unsigned short* __restrict__ Dl = (nt < 8) ? Qlo : Klo;
        #pragma unroll
        for (int nf = 0; nf < 4; ++nf) {
            const int n = n0 + 64 * wc + 16 * nf + li;
            const float bb = bias[n & 1023];
            const int hh = (n >> 6) & 15, e = n & 63;
            #pragma unroll
            for (int mf = 0; mf < 4; ++mf)
                #pragma unroll
                for (int r = 0; r < 4; ++r) {
                    const int m = m0 + 64 * wr + 16 * mf + 4 * g + r;
                    const int bat = m >> 11, s = m & 2047;
                    const float v = acc[mf][nf][r] + bb;
                    const size_t idx = ((size_t)(bat * NH + hh) * SEQ + s) * DE + e;
                    const unsigned short hi = f2bf(v);
                    Dh[idx] = hi;
                    Dl[idx] = f2bf(v - bf2f(hi));
                }
        }
    } else {
        #pragma unroll
        for (int nf = 0; nf < 4; ++nf) {
            const int n = n0 + 64 * wc + 16 * nf + li;    // 0..1023
            const float bb = bv[n];
            const int hh = n >> 6, e = n & 63;
            #pragma unroll
            for (int mf = 0; mf < 4; ++mf) {
                const int m = m0 + 64 * wr + 16 * mf + 4 * g;   // 4-aligned
                const int bat = m >> 11, s0 = m & 2047;
                ushort4_t pk;
                #pragma unroll
                for (int r = 0; r < 4; ++r) pk[r] = f2bf(acc[mf][nf][r] + bb);
                *reinterpret_cast<ushort4_t*>(
                    &Vt_g[((size_t)(bat * NH + hh) * DE + e) * SEQ + s0]) = pk;
            }
        }
    }
}

// ---------------------------------------------------------------------------
// Kernel D: flash attention via MFMA (S^T = mfma(K,Q), O^T = mfma(V^T,P^T)).
// gload_lds + swizzled staging; defer-max; perm-packed P; setprio on MFMA.
// 512 blocks (XCD-swizzled), 4 waves x 32 q-rows each, KV tile 64.
// ---------------------------------------------------------------------------
__global__ __launch_bounds__(256)
void attn_kernel(const unsigned short* __restrict__ Qhi_g,
                 const unsigned short* __restrict__ Qlo_g,
                 const unsigned short* __restrict__ Khi_g,
                 const unsigned short* __restrict__ Klo_g,
                 const unsigned short* __restrict__ Vt_g,
                 float* __restrict__ out)
{
    __shared__ __attribute__((aligned(16))) unsigned short Kh_s[64 * 64];
    __shared__ __attribute__((aligned(16))) unsigned short Kl_s[64 * 64];
    __shared__ __attribute__((aligned(16))) unsigned short Vt_s[64 * 64];

    const int t = threadIdx.x;
    const int w = t >> 6, lane = t & 63, g = lane >> 4, li = lane & 15;
    const int bid = blockIdx.x;
    const int gix = (bid & 7) * 64 + (bid >> 3);      // 512 = 8*64 bijective
    const int qt = gix & 15, h = (gix >> 4) & 15, bat = gix >> 8;
    const size_t bh = (size_t)(bat * NH + h) * SEQ;
    const size_t vb0 = (size_t)(bat * NH + h) * DE * SEQ;   // V^T base [e][s]

    // ---- prologue: hoist Q fragments (B-operand) via LDS ----
    short8 qh[2][2], ql[2][2];    // [cb][ks]
    #pragma unroll
    for (int ro = 0; ro < 2; ++ro) {
        __syncthreads();
        #pragma unroll
        for (int rnd = 0; rnd < 2; ++rnd) {
            const int U = rnd * 256 + t;
            const int r = U >> 3, i = U & 7, u = i ^ (r & 7);
            const int ldso = (rnd * 256 + w * 64) * 8;
            const size_t off = (bh + qt * 128 + ro * 64 + r) * DE + u * 8;
            gld16(Kh_s + ldso, Qhi_g + off);
            gld16(Kl_s + ldso, Qlo_g + off);
        }
        __syncthreads();
        if ((w >> 1) == ro) {
            const int rq = 32 * (w & 1);
            #pragma unroll
            for (int cb = 0; cb < 2; ++cb)
                #pragma unroll
                for (int ks = 0; ks < 2; ++ks) {
                    qh[cb][ks] = lds64(Kh_s, rq + 16 * cb + li, ks * 4 + g);
                    ql[cb][ks] = lds64(Kl_s, rq + 16 * cb + li, ks * 4 + g);
                }
        }
    }

    const f32x4 zero4 = {0.f, 0.f, 0.f, 0.f};
    f32x4 accO[4][2];
    #pragma unroll
    for (int vb = 0; vb < 4; ++vb) { accO[vb][0] = zero4; accO[vb][1] = zero4; }
    float m_c[2] = {-1e30f, -1e30f}, l_c[2] = {0.f, 0.f};

    for (int kt = 0; kt < SEQ / 64; ++kt) {
        __syncthreads();
        #pragma unroll
        for (int rnd = 0; rnd < 2; ++rnd) {
            const int U = rnd * 256 + t;
            const int r = U >> 3, i = U & 7, u = i ^ (r & 7);
            const int ldso = (rnd * 256 + w * 64) * 8;
            gld16(Kh_s + ldso, Khi_g + (bh + kt * 64 + r) * DE + u * 8);
            gld16(Kl_s + ldso, Klo_g + (bh + kt * 64 + r) * DE + u * 8);
            gld16(Vt_s + ldso, Vt_g + vb0 + (size_t)r * SEQ + kt * 64 + u * 8);
        }
        __syncthreads();

        // ---- QK^T: S^T[key][q], 3-term split ----
        f32x4 st[4][2];
        #pragma unroll
        for (int rb = 0; rb < 4; ++rb) { st[rb][0] = zero4; st[rb][1] = zero4; }
        #pragma unroll
        for (int ks = 0; ks < 2; ++ks) {
            short8 kh[4], kl[4];
            #pragma unroll
            for (int rb = 0; rb < 4; ++rb) {
                kh[rb] = lds64(Kh_s, 16 * rb + li, ks * 4 + g);
                kl[rb] = lds64(Kl_s, 16 * rb + li, ks * 4 + g);
            }
            __builtin_amdgcn_s_setprio(1);
            #pragma unroll
            for (int rb = 0; rb < 4; ++rb)
                #pragma unroll
                for (int cb = 0; cb < 2; ++cb) {
                    st[rb][cb] = mfma16(kh[rb], qh[cb][ks], st[rb][cb]);
                    st[rb][cb] = mfma16(kh[rb], ql[cb][ks], st[rb][cb]);
                    st[rb][cb] = mfma16(kl[rb], qh[cb][ks], st[rb][cb]);
                }
            __builtin_amdgcn_s_setprio(0);
        }

        // ---- online softmax with defer-max (THR=8) ----
        int ppk[4][2][2];
        #pragma unroll
        for (int cb = 0; cb < 2; ++cb) {
            float mx = st[0][cb][0];
            #pragma unroll
            for (int rb = 0; rb < 4; ++rb)
                #pragma unroll
                for (int r = 0; r < 4; ++r) mx = fmaxf(mx, st[rb][cb][r]);
            mx = fmaxf(mx, __shfl_xor(mx, 16));
            mx = fmaxf(mx, __shfl_xor(mx, 32));
            float mn = m_c[cb];
            if (!__all(mx <= mn + 8.f)) {
                mn = fmaxf(mn, mx);
                const float scl = __expf(m_c[cb] - mn);
                l_c[cb] *= scl;
                #pragma unroll
                for (int vb = 0; vb < 4; ++vb) accO[vb][cb] *= scl;
                m_c[cb] = mn;
            }
            float rs = 0.f;
            #pragma unroll
            for (int rb = 0; rb < 4; ++rb) {
                const float p0 = __expf(st[rb][cb][0] - mn);
                const float p1 = __expf(st[rb][cb][1] - mn);
                const float p2 = __expf(st[rb][cb][2] - mn);
                const float p3 = __expf(st[rb][cb][3] - mn);
                rs += (p0 + p1) + (p2 + p3);
                ppk[rb][cb][0] = pkbf(p0, p1);
                ppk[rb][cb][1] = pkbf(p2, p3);
            }
            rs += __shfl_xor(rs, 16);
            rs += __shfl_xor(rs, 32);
            l_c[cb] += rs;
        }

        // ---- PV: O^T += V^T * P^T ----
        #pragma unroll
        for (int ks = 0; ks < 2; ++ks) {
            short8 av[4];
            #pragma unroll
            for (int vb = 0; vb < 4; ++vb)
                av[vb] = lds64(Vt_s, 16 * vb + li, ks * 4 + g);
            #pragma unroll
            for (int cb = 0; cb < 2; ++cb) {
                int dw[4];
                #pragma unroll
                for (int tp = 0; tp < 4; ++tp) {
                    const int tt = tp & 1;
                    const int sl = li + 16 * (2 * (g & 1) + (tp >> 1));
                    const int y0 = __shfl(ppk[2 * ks][cb][tt], sl, 64);
                    const int y1 = __shfl(ppk[2 * ks + 1][cb][tt], sl, 64);
                    dw[tp] = (g >> 1) ? y1 : y0;
                }
                union { int i[4]; short8 s; } u4;
                u4.i[0] = dw[0]; u4.i[1] = dw[1]; u4.i[2] = dw[2]; u4.i[3] = dw[3];
                __builtin_amdgcn_s_setprio(1);
                #pragma unroll
                for (int vb = 0; vb < 4; ++vb)
                    accO[vb][cb] = mfma16(av[vb], u4.s, accO[vb][cb]);
                __builtin_amdgcn_s_setprio(0);
            }
        }
    }

    // ---- epilogue: out[b][s][h*64+vd] = O^T / (l * 8) ----
    #pragma unroll
    for (int cb = 0; cb < 2; ++cb) {
        const float invl = 0.125f / l_c[cb];
        const int s = qt * 128 + 32 * w + 16 * cb + li;
        #pragma unroll
        for (int vb = 0; vb < 4; ++vb) {
            float4 o;
            o.x = accO[vb][cb][0] * invl;
            o.y = accO[vb][cb][1] * invl;
            o.z = accO[vb][cb][2] * invl;
            o.w = accO[vb][cb][3] * invl;
            const int vd = 16 * vb + 4 * g;
            *reinterpret_cast<float4*>(
                &out[((size_t)bat * SEQ + s) * (NH * DE) + h * DE + vd]) = o;
        }
    }
}

extern "C" void kernel_launch(void* const* d_in, const int* in_sizes, int n_in,
                              void* d_out, int out_size, void* d_ws, size_t ws_size,
                              hipStream_t stream)
{
    (void)in_sizes; (void)n_in; (void)out_size; (void)ws_size;
    const float* x  = (const float*)d_in[0];
    const float* Wq = (const float*)d_in[1];
    const float* bq = (const float*)d_in[2];
    const float* Wk = (const float*)d_in[3];
    const float* bk = (const float*)d_in[4];
    const float* Wv = (const float*)d_in[5];
    const float* bv = (const float*)d_in[6];
    float* out = (float*)d_out;

    // d_out scratch: Wt hi/lo (12.58 MB <= 16.78 MB), dead before attn writes.
    unsigned short* Wt_hi = (unsigned short*)d_out;
    unsigned short* Wt_lo = Wt_hi + (size_t)3072 * DIN;

    // d_ws (48 MB): [xh 8][xl 8 -> Vt after QK pass][Qhi][Qlo][Khi][Klo]
    const size_t per = (size_t)BATCH * NH * SEQ * DE;   // 4 Mi elems = 8 MB bf16
    unsigned short* ws  = (unsigned short*)d_ws;
    unsigned short* xh  = ws;
    unsigned short* xl  = ws + per;        // reused as Vt_g by proj<1>
    unsigned short* Qhi = ws + 2 * per;
    unsigned short* Qlo = ws + 3 * per;
    unsigned short* Khi = ws + 4 * per;
    unsigned short* Klo = ws + 5 * per;
    unsigned short* Vt  = xl;

    xsplit_kernel<<<2048, 256, 0, stream>>>(x, xh, xl);
    wsplit_kernel<<<dim3(16, NH, 3), 256, 0, stream>>>(Wq, Wk, Wv, Wt_hi, Wt_lo);
    proj_kernel<0><<<512, 256, 0, stream>>>(xh, xl, Wt_hi, Wt_lo, bq, bk, bv,
                                            Qhi, Qlo, Khi, Klo, Vt);
    proj_kernel<1><<<256, 256, 0, stream>>>(xh, xl, Wt_hi, Wt_lo, bq, bk, bv,
                                            Qhi, Qlo, Khi, Klo, Vt);
    attn_kernel<<<512, 256, 0, stream>>>(Qhi, Qlo, Khi, Klo, Vt, out);
}

// Round 4
// 179.969 us; speedup vs baseline: 6.2216x; 1.0632x over previous
//
#include <hip/hip_runtime.h>

#define BATCH 2
#define SEQ   2048
#define DIN   1024
#define NH    16
#define DE    64
#define NT_KV (SEQ / 64)

typedef __attribute__((ext_vector_type(8))) short short8;
typedef __attribute__((ext_vector_type(4))) float f32x4;
typedef __attribute__((ext_vector_type(4))) unsigned short ushort4_t;

static __device__ __forceinline__ unsigned short f2bf(float f) {
    union { float f; unsigned int u; } x; x.f = f;
    unsigned int r = x.u + 0x7fffu + ((x.u >> 16) & 1u);   // RNE
    return (unsigned short)(r >> 16);
}
static __device__ __forceinline__ float bf2f(unsigned short h) {
    union { unsigned int u; float f; } x; x.u = ((unsigned int)h) << 16;
    return x.f;
}
static __device__ __forceinline__ f32x4 mfma16(short8 a, short8 b, f32x4 c) {
    return __builtin_amdgcn_mfma_f32_16x16x32_bf16(a, b, c, 0, 0, 0);
}
// async global->LDS, 16B per lane; dest = wave-uniform base + lane*16
static __device__ __forceinline__ void gld16(unsigned short* l, const unsigned short* g) {
    __builtin_amdgcn_global_load_lds(
        (const __attribute__((address_space(1))) void*)g,
        (__attribute__((address_space(3))) void*)l, 16, 0, 0);
}
// pack two f32 -> packed bf16 (round-half-up) in one v_perm
static __device__ __forceinline__ int pkbf(float a, float b) {
    union { float f; unsigned int u; } x, y; x.f = a; y.f = b;
    return __builtin_amdgcn_perm(y.u + 0x8000u, x.u + 0x8000u, 0x07060302);
}
// swizzled b128 read from a [R][64] bf16 tile (128B rows, XOR (row&7) on 16B units)
static __device__ __forceinline__ short8 lds64(const unsigned short* buf, int row, int u) {
    return *reinterpret_cast<const short8*>(buf + row * 64 + ((u ^ (row & 7)) << 3));
}
// swizzled b128 read from a [R][32] bf16 tile (row-pair scheme)
static __device__ __forceinline__ short8 lds32(const unsigned short* buf, int row, int g) {
    int p = row >> 1, e = ((row & 1) << 2) | g;
    return *reinterpret_cast<const short8*>(buf + p * 64 + ((e ^ (p & 7)) << 3));
}

// ---------------------------------------------------------------------------
// Kernel A: split x (fp32) -> x_hi, x_lo (bf16). 2048 blocks x 256, 8 elem/thr.
// ---------------------------------------------------------------------------
__global__ __launch_bounds__(256)
void xsplit_kernel(const float* __restrict__ x,
                   unsigned short* __restrict__ xh, unsigned short* __restrict__ xl)
{
    size_t i0 = ((size_t)blockIdx.x * 256 + threadIdx.x) * 8;
    float4 a = *reinterpret_cast<const float4*>(&x[i0]);
    float4 b = *reinterpret_cast<const float4*>(&x[i0 + 4]);
    float vv[8] = {a.x, a.y, a.z, a.w, b.x, b.y, b.z, b.w};
    short8 sh, sl;
    #pragma unroll
    for (int j = 0; j < 8; ++j) {
        unsigned short hh = f2bf(vv[j]);
        sh[j] = (short)hh;
        sl[j] = (short)f2bf(vv[j] - bf2f(hh));
    }
    *reinterpret_cast<short8*>(&xh[i0]) = sh;
    *reinterpret_cast<short8*>(&xl[i0]) = sl;
}

// ---------------------------------------------------------------------------
// Kernel B: W transpose + bf16 hi/lo split.
// ---------------------------------------------------------------------------
__global__ __launch_bounds__(256)
void wsplit_kernel(const float* __restrict__ Wq, const float* __restrict__ Wk,
                   const float* __restrict__ Wv,
                   unsigned short* __restrict__ Wt_hi,
                   unsigned short* __restrict__ Wt_lo)
{
    const int dt = blockIdx.x, h = blockIdx.y, z = blockIdx.z;
    const float* __restrict__ W = (z == 0) ? Wq : (z == 1) ? Wk : Wv;
    __shared__ float Ws[64][65];
    const int t = threadIdx.x;
    const int d0 = dt * 64;
    #pragma unroll
    for (int u = 0; u < 4; ++u) {
        int id = t + 256 * u;
        int d = id >> 4, e0 = (id & 15) * 4;
        float4 v = *reinterpret_cast<const float4*>(&W[(size_t)(h * DIN + d0 + d) * DE + e0]);
        Ws[d][e0] = v.x; Ws[d][e0 + 1] = v.y; Ws[d][e0 + 2] = v.z; Ws[d][e0 + 3] = v.w;
    }
    __syncthreads();
    #pragma unroll
    for (int u = 0; u < 2; ++u) {
        int id = t + 256 * u;
        int e = id >> 3, dc = (id & 7) * 8;
        short8 sh, sl;
        #pragma unroll
        for (int j = 0; j < 8; ++j) {
            float v = Ws[dc + j][e];
            unsigned short hh = f2bf(v);
            sh[j] = (short)hh;
            sl[j] = (short)f2bf(v - bf2f(hh));
        }
        int n = z * 1024 + h * 64 + e;
        size_t off = (size_t)n * DIN + d0 + dc;
        *reinterpret_cast<short8*>(&Wt_hi[off]) = sh;
        *reinterpret_cast<short8*>(&Wt_lo[off]) = sl;
    }
}

// ---------------------------------------------------------------------------
// Kernel C: projection GEMM, double-buffered gload_lds pipeline.
// PHASE 0: Q,K (3-term split, N=2048, 512 blocks); Q scaled by log2(e).
// PHASE 1: V  (1-term, N=1024, 256 blocks) -> Vt_g [b][h][e][s]
// ---------------------------------------------------------------------------
template <int PHASE>
__global__ __launch_bounds__(256)
void proj_kernel(const unsigned short* __restrict__ xh, const unsigned short* __restrict__ xl,
                 const unsigned short* __restrict__ Wt_hi, const unsigned short* __restrict__ Wt_lo,
                 const float* __restrict__ bq, const float* __restrict__ bk,
                 const float* __restrict__ bv,
                 unsigned short* __restrict__ Qhi, unsigned short* __restrict__ Qlo,
                 unsigned short* __restrict__ Khi, unsigned short* __restrict__ Klo,
                 unsigned short* __restrict__ Vt_g)
{
    constexpr int SB = (PHASE == 0) ? 4 : 2;   // buffers per set
    __shared__ __attribute__((aligned(16))) unsigned short smem[2 * SB][128 * 32];

    const int t = threadIdx.x;
    const int w = t >> 6, lane = t & 63, g = lane >> 4, li = lane & 15;
    const int wr = w >> 1, wc = w & 1;

    const int bid = blockIdx.x;
    const int per = (PHASE == 0 ? 512 : 256) >> 3;
    const int gix = (bid & 7) * per + (bid >> 3);
    int mt, nt;
    if (PHASE == 0) { nt = gix & 15; mt = gix >> 4; }
    else            { nt = gix & 7;  mt = gix >> 3; }
    const int m0 = mt * 128, n0 = nt * 128;
    const int wrow = (PHASE == 0 ? 0 : 2048) + n0;

    auto stage = [&](int set, int k0) {
        #pragma unroll
        for (int rnd = 0; rnd < 2; ++rnd) {
            const int U = rnd * 256 + t;
            const int p = U >> 3, i = U & 7, e = i ^ (p & 7);
            const int r = 2 * p + (e >> 2), c = (e & 3) * 8;
            const int ldso = (rnd * 256 + w * 64) * 8;
            const size_t aoff = (size_t)(m0 + r) * DIN + k0 + c;
            const size_t boff = (size_t)(wrow + r) * DIN + k0 + c;
            gld16(smem[SB * set + 0] + ldso, xh + aoff);
            gld16(smem[SB * set + 1] + ldso, Wt_hi + boff);
            if constexpr (PHASE == 0) {
                gld16(smem[SB * set + 2] + ldso, xl + aoff);
                gld16(smem[SB * set + 3] + ldso, Wt_lo + boff);
            }
        }
    };

    const f32x4 zero4 = {0.f, 0.f, 0.f, 0.f};
    f32x4 acc[4][4];
    #pragma unroll
    for (int i = 0; i < 4; ++i)
        #pragma unroll
        for (int j = 0; j < 4; ++j) acc[i][j] = zero4;

    stage(0, 0);
    __syncthreads();

    for (int k0 = 0; k0 < DIN; k0 += 32) {
        const int cur = (k0 >> 5) & 1;
        if (k0 + 32 < DIN) stage(cur ^ 1, k0 + 32);   // prefetch next K-step

        short8 ah[4], bh[4], al[4], bl[4];
        #pragma unroll
        for (int mf = 0; mf < 4; ++mf) ah[mf] = lds32(smem[SB * cur + 0], 64 * wr + 16 * mf + li, g);
        #pragma unroll
        for (int nf = 0; nf < 4; ++nf) bh[nf] = lds32(smem[SB * cur + 1], 64 * wc + 16 * nf + li, g);
        if constexpr (PHASE == 0) {
            #pragma unroll
            for (int mf = 0; mf < 4; ++mf) al[mf] = lds32(smem[SB * cur + 2], 64 * wr + 16 * mf + li, g);
            #pragma unroll
            for (int nf = 0; nf < 4; ++nf) bl[nf] = lds32(smem[SB * cur + 3], 64 * wc + 16 * nf + li, g);
        }
        __builtin_amdgcn_s_setprio(1);
        #pragma unroll
        for (int mf = 0; mf < 4; ++mf)
            #pragma unroll
            for (int nf = 0; nf < 4; ++nf) {
                acc[mf][nf] = mfma16(ah[mf], bh[nf], acc[mf][nf]);
                if constexpr (PHASE == 0) {
                    acc[mf][nf] = mfma16(ah[mf], bl[nf], acc[mf][nf]);
                    acc[mf][nf] = mfma16(al[mf], bh[nf], acc[mf][nf]);
                }
            }
        __builtin_amdgcn_s_setprio(0);
        __syncthreads();   // drains vmcnt (prefetch) + lgkm; one barrier per K-step
    }

    if constexpr (PHASE == 0) {
        const bool isQ = (nt < 8);
        const float* __restrict__ bias = isQ ? bq : bk;
        unsigned short* __restrict__ Dh = isQ ? Qhi : Khi;
        unsigned short* __restrict__ Dl = isQ ? Qlo : Klo;
        const float qscl = isQ ? 1.4426950408889634f : 1.0f;   // log2(e) folded into Q
        #pragma unroll
        for (int nf = 0; nf < 4; ++nf) {
            const int n = n0 + 64 * wc + 16 * nf + li;
            const float bb = bias[n & 1023];
            const int hh = (n >> 6) & 15, e = n & 63;
            #pragma unroll
            for (int mf = 0; mf < 4; ++mf)
                #pragma unroll
                for (int r = 0; r < 4; ++r) {
                    const int m = m0 + 64 * wr + 16 * mf + 4 * g + r;
                    const int bat = m >> 11, s = m & 2047;
                    const float v = (acc[mf][nf][r] + bb) * qscl;
                    const size_t idx = ((size_t)(bat * NH + hh) * SEQ + s) * DE + e;
                    const unsigned short hi = f2bf(v);
                    Dh[idx] = hi;
                    Dl[idx] = f2bf(v - bf2f(hi));
                }
        }
    } else {
        #pragma unroll
        for (int nf = 0; nf < 4; ++nf) {
            const int n = n0 + 64 * wc + 16 * nf + li;
            const float bb = bv[n];
            const int hh = n >> 6, e = n & 63;
            #pragma unroll
            for (int mf = 0; mf < 4; ++mf) {
                const int m = m0 + 64 * wr + 16 * mf + 4 * g;
                const int bat = m >> 11, s0 = m & 2047;
                ushort4_t pk;
                #pragma unroll
                for (int r = 0; r < 4; ++r) pk[r] = f2bf(acc[mf][nf][r] + bb);
                *reinterpret_cast<ushort4_t*>(
                    &Vt_g[((size_t)(bat * NH + hh) * DE + e) * SEQ + s0]) = pk;
            }
        }
    }
}

// ---------------------------------------------------------------------------
// Kernel D: flash attention, 512 threads (8 waves x 16 q-rows), KV tile 64,
// double-buffered gload_lds pipeline (one barrier per tile), exp2 softmax,
// defer-max, perm-packed P, setprio on MFMA. 512 blocks, XCD-swizzled.
// ---------------------------------------------------------------------------
__global__ __launch_bounds__(512)
void attn_kernel(const unsigned short* __restrict__ Qhi_g,
                 const unsigned short* __restrict__ Qlo_g,
                 const unsigned short* __restrict__ Khi_g,
                 const unsigned short* __restrict__ Klo_g,
                 const unsigned short* __restrict__ Vt_g,
                 float* __restrict__ out)
{
    __shared__ __attribute__((aligned(16))) unsigned short smem[6][64 * 64];

    const int t = threadIdx.x;
    const int w = t >> 6, lane = t & 63, g = lane >> 4, li = lane & 15;
    const int bid = blockIdx.x;
    const int gix = (bid & 7) * 64 + (bid >> 3);      // 512 = 8*64 bijective
    const int qt = gix & 15, h = (gix >> 4) & 15, bat = gix >> 8;
    const size_t bh = (size_t)(bat * NH + h) * SEQ;
    const size_t vb0 = (size_t)(bat * NH + h) * DE * SEQ;   // V^T base [e][s]

    // staging coords: 512 units of 16B cover one 64x64 bf16 tile
    const int r = t >> 3, iu = t & 7, uu = iu ^ (r & 7);
    const int ldso = w * 512;                          // wave-uniform base (elems)

    // ---- stage Q (128x64 hi+lo), hoist fragments ----
    gld16(smem[0] + ldso, Qhi_g + (bh + qt * 128 + r) * DE + uu * 8);
    gld16(smem[1] + ldso, Qhi_g + (bh + qt * 128 + 64 + r) * DE + uu * 8);
    gld16(smem[2] + ldso, Qlo_g + (bh + qt * 128 + r) * DE + uu * 8);
    gld16(smem[3] + ldso, Qlo_g + (bh + qt * 128 + 64 + r) * DE + uu * 8);
    __syncthreads();

    short8 qh[2], ql[2];   // wave w owns q rows 16w..16w+15
    {
        const int half = w >> 2, row = 16 * (w & 3) + li;
        #pragma unroll
        for (int ks = 0; ks < 2; ++ks) {
            qh[ks] = lds64(smem[half], row, ks * 4 + g);
            ql[ks] = lds64(smem[2 + half], row, ks * 4 + g);
        }
    }
    __syncthreads();   // frags in regs; LDS free

    // ---- stage tile 0 into set 0 ----
    gld16(smem[0] + ldso, Khi_g + (bh + r) * DE + uu * 8);
    gld16(smem[1] + ldso, Klo_g + (bh + r) * DE + uu * 8);
    gld16(smem[2] + ldso, Vt_g + vb0 + (size_t)r * SEQ + uu * 8);
    __syncthreads();

    const f32x4 zero4 = {0.f, 0.f, 0.f, 0.f};
    f32x4 accO[4];
    #pragma unroll
    for (int vb = 0; vb < 4; ++vb) accO[vb] = zero4;
    float m_c = -1e30f, l_c = 0.f;

    for (int kt = 0; kt < NT_KV; ++kt) {
        const int cs = (kt & 1) * 3;
        if (kt + 1 < NT_KV) {                          // prefetch next tile
            const int ns = 3 - cs;
            gld16(smem[ns + 0] + ldso, Khi_g + (bh + (kt + 1) * 64 + r) * DE + uu * 8);
            gld16(smem[ns + 1] + ldso, Klo_g + (bh + (kt + 1) * 64 + r) * DE + uu * 8);
            gld16(smem[ns + 2] + ldso, Vt_g + vb0 + (size_t)r * SEQ + (kt + 1) * 64 + uu * 8);
        }

        // ---- QK^T: S^T[key][q], 3-term split ----
        f32x4 st[4];
        #pragma unroll
        for (int rb = 0; rb < 4; ++rb) st[rb] = zero4;
        #pragma unroll
        for (int ks = 0; ks < 2; ++ks) {
            short8 kh[4], kl[4];
            #pragma unroll
            for (int rb = 0; rb < 4; ++rb) {
                kh[rb] = lds64(smem[cs + 0], 16 * rb + li, ks * 4 + g);
                kl[rb] = lds64(smem[cs + 1], 16 * rb + li, ks * 4 + g);
            }
            __builtin_amdgcn_s_setprio(1);
            #pragma unroll
            for (int rb = 0; rb < 4; ++rb) {
                st[rb] = mfma16(kh[rb], qh[ks], st[rb]);
                st[rb] = mfma16(kh[rb], ql[ks], st[rb]);
                st[rb] = mfma16(kl[rb], qh[ks], st[rb]);
            }
            __builtin_amdgcn_s_setprio(0);
        }

        // ---- online softmax (base-2; Q pre-scaled by log2 e), defer-max ----
        int ppk[4][2];
        {
            float mx = st[0][0];
            #pragma unroll
            for (int rb = 0; rb < 4; ++rb)
                #pragma unroll
                for (int rr = 0; rr < 4; ++rr) mx = fmaxf(mx, st[rb][rr]);
            mx = fmaxf(mx, __shfl_xor(mx, 16));
            mx = fmaxf(mx, __shfl_xor(mx, 32));
            float mn = m_c;
            if (!__all(mx <= mn + 8.f)) {
                mn = fmaxf(mn, mx);
                const float scl = exp2f(m_c - mn);
                l_c *= scl;
                #pragma unroll
                for (int vb = 0; vb < 4; ++vb) accO[vb] *= scl;
                m_c = mn;
            }
            float rs = 0.f;
            #pragma unroll
            for (int rb = 0; rb < 4; ++rb) {
                const float p0 = exp2f(st[rb][0] - mn);
                const float p1 = exp2f(st[rb][1] - mn);
                const float p2 = exp2f(st[rb][2] - mn);
                const float p3 = exp2f(st[rb][3] - mn);
                rs += (p0 + p1) + (p2 + p3);
                ppk[rb][0] = pkbf(p0, p1);
                ppk[rb][1] = pkbf(p2, p3);
            }
            rs += __shfl_xor(rs, 16);
            rs += __shfl_xor(rs, 32);
            l_c += rs;
        }

        // ---- PV: O^T += V^T * P^T ----
        #pragma unroll
        for (int ks = 0; ks < 2; ++ks) {
            short8 av[4];
            #pragma unroll
            for (int vb = 0; vb < 4; ++vb)
                av[vb] = lds64(smem[cs + 2], 16 * vb + li, ks * 4 + g);
            int dw[4];
            #pragma unroll
            for (int tp = 0; tp < 4; ++tp) {
                const int tt = tp & 1;
                const int sl = li + 16 * (2 * (g & 1) + (tp >> 1));
                const int y0 = __shfl(ppk[2 * ks][tt], sl, 64);
                const int y1 = __shfl(ppk[2 * ks + 1][tt], sl, 64);
                dw[tp] = (g >> 1) ? y1 : y0;
            }
            union { int i[4]; short8 s; } u4;
            u4.i[0] = dw[0]; u4.i[1] = dw[1]; u4.i[2] = dw[2]; u4.i[3] = dw[3];
            __builtin_amdgcn_s_setprio(1);
            #pragma unroll
            for (int vb = 0; vb < 4; ++vb)
                accO[vb] = mfma16(av[vb], u4.s, accO[vb]);
            __builtin_amdgcn_s_setprio(0);
        }

        __syncthreads();   // drains prefetch vmcnt + lgkm; one barrier per tile
    }

    // ---- epilogue: out[b][s][h*64+vd] = O^T / (l * 8) ----
    {
        const float invl = 0.125f / l_c;
        const int s = qt * 128 + 16 * w + li;
        #pragma unroll
        for (int vb = 0; vb < 4; ++vb) {
            float4 o;
            o.x = accO[vb][0] * invl;
            o.y = accO[vb][1] * invl;
            o.z = accO[vb][2] * invl;
            o.w = accO[vb][3] * invl;
            const int vd = 16 * vb + 4 * g;
            *reinterpret_cast<float4*>(
                &out[((size_t)bat * SEQ + s) * (NH * DE) + h * DE + vd]) = o;
        }
    }
}

extern "C" void kernel_launch(void* const* d_in, const int* in_sizes, int n_in,
                              void* d_out, int out_size, void* d_ws, size_t ws_size,
                              hipStream_t stream)
{
    (void)in_sizes; (void)n_in; (void)out_size; (void)ws_size;
    const float* x  = (const float*)d_in[0];
    const float* Wq = (const float*)d_in[1];
    const float* bq = (const float*)d_in[2];
    const float* Wk = (const float*)d_in[3];
    const float* bk = (const float*)d_in[4];
    const float* Wv = (const float*)d_in[5];
    const float* bv = (const float*)d_in[6];
    float* out = (float*)d_out;

    // d_out scratch: Wt hi/lo (12.58 MB <= 16.78 MB), dead before attn writes.
    unsigned short* Wt_hi = (unsigned short*)d_out;
    unsigned short* Wt_lo = Wt_hi + (size_t)3072 * DIN;

    // d_ws (48 MB): [xh 8][xl 8 -> Vt after QK pass][Qhi][Qlo][Khi][Klo]
    const size_t per = (size_t)BATCH * NH * SEQ * DE;
    unsigned short* ws  = (unsigned short*)d_ws;
    unsigned short* xh  = ws;
    unsigned short* xl  = ws + per;        // reused as Vt_g by proj<1>
    unsigned short* Qhi = ws + 2 * per;
    unsigned short* Qlo = ws + 3 * per;
    unsigned short* Khi = ws + 4 * per;
    unsigned short* Klo = ws + 5 * per;
    unsigned short* Vt  = xl;

    xsplit_kernel<<<2048, 256, 0, stream>>>(x, xh, xl);
    wsplit_kernel<<<dim3(16, NH, 3), 256, 0, stream>>>(Wq, Wk, Wv, Wt_hi, Wt_lo);
    proj_kernel<0><<<512, 256, 0, stream>>>(xh, xl, Wt_hi, Wt_lo, bq, bk, bv,
                                            Qhi, Qlo, Khi, Klo, Vt);
    proj_kernel<1><<<256, 256, 0, stream>>>(xh, xl, Wt_hi, Wt_lo, bq, bk, bv,
                                            Qhi, Qlo, Khi, Klo, Vt);
    attn_kernel<<<512, 512, 0, stream>>>(Qhi, Qlo, Khi, Klo, Vt, out);
}

// Round 5
// 120.648 us; speedup vs baseline: 9.2807x; 1.4917x over previous
//
#include <hip/hip_runtime.h>

#define BATCH 2
#define SEQ   2048
#define DIN   1024
#define NH    16
#define DE    64
#define NT_KV (SEQ / 64)

typedef __attribute__((ext_vector_type(8))) short short8;
typedef __attribute__((ext_vector_type(4))) float f32x4;
typedef __attribute__((ext_vector_type(4))) unsigned short ushort4_t;
typedef __attribute__((ext_vector_type(8))) _Float16 f16x8;
typedef __attribute__((ext_vector_type(2))) _Float16 f16x2;

static __device__ __forceinline__ f32x4 mfmaF(short8 a, short8 b, f32x4 c) {
    return __builtin_amdgcn_mfma_f32_16x16x32_f16(
        __builtin_bit_cast(f16x8, a), __builtin_bit_cast(f16x8, b), c, 0, 0, 0);
}
// async global->LDS, 16B per lane; dest = wave-uniform base + lane*16
static __device__ __forceinline__ void gld16(unsigned short* l, const unsigned short* g) {
    __builtin_amdgcn_global_load_lds(
        (const __attribute__((address_space(1))) void*)g,
        (__attribute__((address_space(3))) void*)l, 16, 0, 0);
}
// pack two f32 -> packed f16 dword (v_cvt_pkrtz_f16_f32, single instr)
static __device__ __forceinline__ int pkf16(float a, float b) {
    return __builtin_bit_cast(int, __builtin_amdgcn_cvt_pkrtz(a, b));
}
static __device__ __forceinline__ unsigned short f2h(float f) {
    return __builtin_bit_cast(unsigned short, (_Float16)f);   // RNE
}
// swizzled b128 read from a [R][64] f16 tile (128B rows, XOR (row&7) on 16B units)
static __device__ __forceinline__ short8 lds64(const unsigned short* buf, int row, int u) {
    return *reinterpret_cast<const short8*>(buf + row * 64 + ((u ^ (row & 7)) << 3));
}
// swizzled b128 read from a [R][32] f16 tile (row-pair scheme)
static __device__ __forceinline__ short8 lds32(const unsigned short* buf, int row, int g) {
    int p = row >> 1, e = ((row & 1) << 2) | g;
    return *reinterpret_cast<const short8*>(buf + p * 64 + ((e ^ (p & 7)) << 3));
}

// ---------------------------------------------------------------------------
// Kernel A: convert x (fp32) -> fp16. 2048 blocks x 256, 8 elem/thr.
// ---------------------------------------------------------------------------
__global__ __launch_bounds__(256)
void xcvt_kernel(const float* __restrict__ x, unsigned short* __restrict__ xo)
{
    size_t i0 = ((size_t)blockIdx.x * 256 + threadIdx.x) * 8;
    float4 a = *reinterpret_cast<const float4*>(&x[i0]);
    float4 b = *reinterpret_cast<const float4*>(&x[i0 + 4]);
    float vv[8] = {a.x, a.y, a.z, a.w, b.x, b.y, b.z, b.w};
    short8 sh;
    #pragma unroll
    for (int j = 0; j < 8; ++j) sh[j] = (short)f2h(vv[j]);
    *reinterpret_cast<short8*>(&xo[i0]) = sh;
}

// ---------------------------------------------------------------------------
// Kernel B: W transpose + fp16 convert. Wt rows: n = z*1024 + h*64 + e.
// ---------------------------------------------------------------------------
__global__ __launch_bounds__(256)
void wcvt_kernel(const float* __restrict__ Wq, const float* __restrict__ Wk,
                 const float* __restrict__ Wv, unsigned short* __restrict__ Wt)
{
    const int dt = blockIdx.x, h = blockIdx.y, z = blockIdx.z;
    const float* __restrict__ W = (z == 0) ? Wq : (z == 1) ? Wk : Wv;
    __shared__ float Ws[64][65];
    const int t = threadIdx.x;
    const int d0 = dt * 64;
    #pragma unroll
    for (int u = 0; u < 4; ++u) {
        int id = t + 256 * u;
        int d = id >> 4, e0 = (id & 15) * 4;
        float4 v = *reinterpret_cast<const float4*>(&W[(size_t)(h * DIN + d0 + d) * DE + e0]);
        Ws[d][e0] = v.x; Ws[d][e0 + 1] = v.y; Ws[d][e0 + 2] = v.z; Ws[d][e0 + 3] = v.w;
    }
    __syncthreads();
    #pragma unroll
    for (int u = 0; u < 2; ++u) {
        int id = t + 256 * u;
        int e = id >> 3, dc = (id & 7) * 8;
        short8 sh;
        #pragma unroll
        for (int j = 0; j < 8; ++j) sh[j] = (short)f2h(Ws[dc + j][e]);
        int n = z * 1024 + h * 64 + e;
        *reinterpret_cast<short8*>(&Wt[(size_t)n * DIN + d0 + dc]) = sh;
    }
}

// ---------------------------------------------------------------------------
// Kernel C: fused QKV projection GEMM, fp16 1-term, double-buffered gload_lds.
// C[m][n] = x[m]·Wt[n] + b;  M=4096, N=3072. Tile 128x128xK32, 4 waves.
// Q (x log2e) and K stored fp16 [b][h][s][e]; V stored fp16 transposed [b][h][e][s].
// 768 blocks, XCD-swizzled.
// ---------------------------------------------------------------------------
__global__ __launch_bounds__(256)
void proj_kernel(const unsigned short* __restrict__ xf,
                 const unsigned short* __restrict__ Wt,
                 const float* __restrict__ bq, const float* __restrict__ bk,
                 const float* __restrict__ bv,
                 unsigned short* __restrict__ Qf, unsigned short* __restrict__ Kf,
                 unsigned short* __restrict__ Vt_g)
{
    __shared__ __attribute__((aligned(16))) unsigned short smem[4][128 * 32];

    const int t = threadIdx.x;
    const int w = t >> 6, lane = t & 63, g = lane >> 4, li = lane & 15;
    const int wr = w >> 1, wc = w & 1;

    const int bid = blockIdx.x;
    const int gix = (bid & 7) * 96 + (bid >> 3);   // 768 = 8*96 bijective
    const int nt = gix % 24, mt = gix / 24;
    const int m0 = mt * 128, n0 = nt * 128;

    auto stage = [&](int set, int k0) {
        #pragma unroll
        for (int rnd = 0; rnd < 2; ++rnd) {
            const int U = rnd * 256 + t;
            const int p = U >> 3, i = U & 7, e = i ^ (p & 7);
            const int r = 2 * p + (e >> 2), c = (e & 3) * 8;
            const int ldso = (rnd * 256 + w * 64) * 8;
            gld16(smem[2 * set + 0] + ldso, xf + (size_t)(m0 + r) * DIN + k0 + c);
            gld16(smem[2 * set + 1] + ldso, Wt + (size_t)(n0 + r) * DIN + k0 + c);
        }
    };

    const f32x4 zero4 = {0.f, 0.f, 0.f, 0.f};
    f32x4 acc[4][4];
    #pragma unroll
    for (int i = 0; i < 4; ++i)
        #pragma unroll
        for (int j = 0; j < 4; ++j) acc[i][j] = zero4;

    stage(0, 0);
    __syncthreads();

    for (int k0 = 0; k0 < DIN; k0 += 32) {
        const int cur = (k0 >> 5) & 1;
        if (k0 + 32 < DIN) stage(cur ^ 1, k0 + 32);

        short8 ah[4], bh[4];
        #pragma unroll
        for (int mf = 0; mf < 4; ++mf) ah[mf] = lds32(smem[2 * cur + 0], 64 * wr + 16 * mf + li, g);
        #pragma unroll
        for (int nf = 0; nf < 4; ++nf) bh[nf] = lds32(smem[2 * cur + 1], 64 * wc + 16 * nf + li, g);
        __builtin_amdgcn_s_setprio(1);
        #pragma unroll
        for (int mf = 0; mf < 4; ++mf)
            #pragma unroll
            for (int nf = 0; nf < 4; ++nf)
                acc[mf][nf] = mfmaF(ah[mf], bh[nf], acc[mf][nf]);
        __builtin_amdgcn_s_setprio(0);
        __syncthreads();
    }

    const int z = n0 >> 10;   // 0:Q 1:K 2:V (uniform per block)
    if (z < 2) {
        const bool isQ = (z == 0);
        const float* __restrict__ bias = isQ ? bq : bk;
        unsigned short* __restrict__ D = isQ ? Qf : Kf;
        const float qscl = isQ ? 1.4426950408889634f : 1.0f;   // log2(e) into Q
        #pragma unroll
        for (int nf = 0; nf < 4; ++nf) {
            const int n = n0 + 64 * wc + 16 * nf + li;
            const float bb = bias[n & 1023];
            const int hh = (n >> 6) & 15, e = n & 63;
            #pragma unroll
            for (int mf = 0; mf < 4; ++mf)
                #pragma unroll
                for (int r = 0; r < 4; ++r) {
                    const int m = m0 + 64 * wr + 16 * mf + 4 * g + r;
                    const int bat = m >> 11, s = m & 2047;
                    D[((size_t)(bat * NH + hh) * SEQ + s) * DE + e] =
                        f2h((acc[mf][nf][r] + bb) * qscl);
                }
        }
    } else {
        #pragma unroll
        for (int nf = 0; nf < 4; ++nf) {
            const int n = n0 + 64 * wc + 16 * nf + li;
            const float bb = bv[n & 1023];
            const int hh = (n >> 6) & 15, e = n & 63;
            #pragma unroll
            for (int mf = 0; mf < 4; ++mf) {
                const int m = m0 + 64 * wr + 16 * mf + 4 * g;
                const int bat = m >> 11, s0 = m & 2047;
                ushort4_t pk;
                #pragma unroll
                for (int r = 0; r < 4; ++r) pk[r] = f2h(acc[mf][nf][r] + bb);
                *reinterpret_cast<ushort4_t*>(
                    &Vt_g[((size_t)(bat * NH + hh) * DE + e) * SEQ + s0]) = pk;
            }
        }
    }
}

// ---------------------------------------------------------------------------
// Kernel D: flash attention, fp16 1-term. 512 threads (8 waves x 16 q-rows),
// KV tile 64, double-buffered gload_lds (one barrier/tile), exp2 softmax with
// defer-max (P <= 2^8, fp16-safe), cvt_pkrtz P-pack, hoisted LDS offsets.
// 512 blocks, XCD-swizzled.
// ---------------------------------------------------------------------------
__global__ __launch_bounds__(512)
void attn_kernel(const unsigned short* __restrict__ Qf,
                 const unsigned short* __restrict__ Kf,
                 const unsigned short* __restrict__ Vt_g,
                 float* __restrict__ out)
{
    __shared__ __attribute__((aligned(16))) unsigned short smem[4][64 * 64];

    const int t = threadIdx.x;
    const int w = t >> 6, lane = t & 63, g = lane >> 4, li = lane & 15;
    const int bid = blockIdx.x;
    const int gix = (bid & 7) * 64 + (bid >> 3);      // 512 = 8*64 bijective
    const int qt = gix & 15, h = (gix >> 4) & 15, bat = gix >> 8;
    const size_t bh = (size_t)(bat * NH + h) * SEQ;
    const size_t vb0 = (size_t)(bat * NH + h) * DE * SEQ;   // V^T base [e][s]

    // staging coords: 512 units of 16B cover one 64x64 f16 tile
    const int r = t >> 3, iu = t & 7, uu = iu ^ (r & 7);
    const int ldso = w * 512;                          // wave-uniform base (elems)

    // hoisted per-lane LDS read offsets (row&7 == li&7 for all rb)
    const int l7 = li & 7;
    const int sl0 = ((0 + g) ^ l7) << 3;               // ks=0 slot
    const int sl1 = ((4 + g) ^ l7) << 3;               // ks=1 slot
    const int rowb = li * 64;

    // ---- stage Q (128x64), hoist fragments ----
    gld16(smem[0] + ldso, Qf + (bh + qt * 128 + r) * DE + uu * 8);
    gld16(smem[1] + ldso, Qf + (bh + qt * 128 + 64 + r) * DE + uu * 8);
    __syncthreads();

    short8 qh[2];   // wave w owns q rows 16w..16w+15
    {
        const unsigned short* qsrc = smem[w >> 2] + (w & 3) * 1024 + rowb;
        qh[0] = *reinterpret_cast<const short8*>(qsrc + sl0);
        qh[1] = *reinterpret_cast<const short8*>(qsrc + sl1);
    }
    __syncthreads();   // frags in regs; LDS free

    // ---- stage tile 0 into set 0 ----
    const unsigned short* kp = Kf + (bh + r) * DE + uu * 8;
    const unsigned short* vp = Vt_g + vb0 + (size_t)r * SEQ + uu * 8;
    gld16(smem[0] + ldso, kp);
    gld16(smem[1] + ldso, vp);
    __syncthreads();

    const f32x4 zero4 = {0.f, 0.f, 0.f, 0.f};
    f32x4 accO[4];
    #pragma unroll
    for (int vb = 0; vb < 4; ++vb) accO[vb] = zero4;
    float m_c = -1e30f, l_c = 0.f;

    for (int kt = 0; kt < NT_KV; ++kt) {
        const int cur = kt & 1;
        if (kt + 1 < NT_KV) {                          // prefetch next tile
            gld16(smem[2 - 2 * cur + 0] + ldso, kp + (kt + 1) * 64 * DE);
            gld16(smem[2 - 2 * cur + 1] + ldso, vp + (kt + 1) * 64);
        }
        const unsigned short* Ks = smem[2 * cur + 0];
        const unsigned short* Vs = smem[2 * cur + 1];

        // ---- QK^T: S^T[key][q] ----
        f32x4 st[4];
        #pragma unroll
        for (int rb = 0; rb < 4; ++rb) st[rb] = zero4;
        {
            short8 k0[4], k1[4];
            #pragma unroll
            for (int rb = 0; rb < 4; ++rb) {
                k0[rb] = *reinterpret_cast<const short8*>(Ks + rowb + rb * 1024 + sl0);
                k1[rb] = *reinterpret_cast<const short8*>(Ks + rowb + rb * 1024 + sl1);
            }
            __builtin_amdgcn_s_setprio(1);
            #pragma unroll
            for (int rb = 0; rb < 4; ++rb) {
                st[rb] = mfmaF(k0[rb], qh[0], st[rb]);
                st[rb] = mfmaF(k1[rb], qh[1], st[rb]);
            }
            __builtin_amdgcn_s_setprio(0);
        }

        // ---- online softmax (base-2; Q pre-scaled), defer-max THR=8 ----
        int ppk[4][2];
        {
            float mx = st[0][0];
            #pragma unroll
            for (int rb = 0; rb < 4; ++rb)
                #pragma unroll
                for (int rr = 0; rr < 4; ++rr) mx = fmaxf(mx, st[rb][rr]);
            mx = fmaxf(mx, __shfl_xor(mx, 16));
            mx = fmaxf(mx, __shfl_xor(mx, 32));
            float mn = m_c;
            if (!__all(mx <= mn + 8.f)) {
                mn = fmaxf(mn, mx);
                const float scl = exp2f(m_c - mn);
                l_c *= scl;
                #pragma unroll
                for (int vb = 0; vb < 4; ++vb) accO[vb] *= scl;
                m_c = mn;
            }
            float rs = 0.f;
            #pragma unroll
            for (int rb = 0; rb < 4; ++rb) {
                const float p0 = exp2f(st[rb][0] - mn);
                const float p1 = exp2f(st[rb][1] - mn);
                const float p2 = exp2f(st[rb][2] - mn);
                const float p3 = exp2f(st[rb][3] - mn);
                rs += (p0 + p1) + (p2 + p3);
                ppk[rb][0] = pkf16(p0, p1);
                ppk[rb][1] = pkf16(p2, p3);
            }
            rs += __shfl_xor(rs, 16);
            rs += __shfl_xor(rs, 32);
            l_c += rs;
        }

        // ---- PV: O^T += V^T * P^T ----
        #pragma unroll
        for (int ks = 0; ks < 2; ++ks) {
            short8 av[4];
            const int slv = ks ? sl1 : sl0;
            #pragma unroll
            for (int vb = 0; vb < 4; ++vb)
                av[vb] = *reinterpret_cast<const short8*>(Vs + rowb + vb * 1024 + slv);
            int dw[4];
            #pragma unroll
            for (int tp = 0; tp < 4; ++tp) {
                const int tt = tp & 1;
                const int sl = li + 16 * (2 * (g & 1) + (tp >> 1));
                const int y0 = __shfl(ppk[2 * ks][tt], sl, 64);
                const int y1 = __shfl(ppk[2 * ks + 1][tt], sl, 64);
                dw[tp] = (g >> 1) ? y1 : y0;
            }
            union { int i[4]; short8 s; } u4;
            u4.i[0] = dw[0]; u4.i[1] = dw[1]; u4.i[2] = dw[2]; u4.i[3] = dw[3];
            __builtin_amdgcn_s_setprio(1);
            #pragma unroll
            for (int vb = 0; vb < 4; ++vb)
                accO[vb] = mfmaF(av[vb], u4.s, accO[vb]);
            __builtin_amdgcn_s_setprio(0);
        }

        __syncthreads();   // drains prefetch vmcnt + lgkm; one barrier per tile
    }

    // ---- epilogue: out[b][s][h*64+vd] = O^T / (l * 8) ----
    {
        const float invl = 0.125f / l_c;
        const int s = qt * 128 + 16 * w + li;
        #pragma unroll
        for (int vb = 0; vb < 4; ++vb) {
            float4 o;
            o.x = accO[vb][0] * invl;
            o.y = accO[vb][1] * invl;
            o.z = accO[vb][2] * invl;
            o.w = accO[vb][3] * invl;
            const int vd = 16 * vb + 4 * g;
            *reinterpret_cast<float4*>(
                &out[((size_t)bat * SEQ + s) * (NH * DE) + h * DE + vd]) = o;
        }
    }
}

extern "C" void kernel_launch(void* const* d_in, const int* in_sizes, int n_in,
                              void* d_out, int out_size, void* d_ws, size_t ws_size,
                              hipStream_t stream)
{
    (void)in_sizes; (void)n_in; (void)out_size; (void)ws_size;
    const float* x  = (const float*)d_in[0];
    const float* Wq = (const float*)d_in[1];
    const float* bq = (const float*)d_in[2];
    const float* Wk = (const float*)d_in[3];
    const float* bk = (const float*)d_in[4];
    const float* Wv = (const float*)d_in[5];
    const float* bv = (const float*)d_in[6];
    float* out = (float*)d_out;

    // d_out scratch: Wt fp16 (6.3 MB <= 16.8 MB), dead before attn writes.
    unsigned short* Wt = (unsigned short*)d_out;

    // d_ws (>=32 MB used): [xf 8MB][Qf 8][Kf 8][Vt 8]
    const size_t per = (size_t)BATCH * NH * SEQ * DE;   // 4 Mi elems = 8 MB fp16
    unsigned short* ws = (unsigned short*)d_ws;
    unsigned short* xf = ws;
    unsigned short* Qf = ws + per;
    unsigned short* Kf = ws + 2 * per;
    unsigned short* Vt = ws + 3 * per;

    xcvt_kernel<<<2048, 256, 0, stream>>>(x, xf);
    wcvt_kernel<<<dim3(16, NH, 3), 256, 0, stream>>>(Wq, Wk, Wv, Wt);
    proj_kernel<<<768, 256, 0, stream>>>(xf, Wt, bq, bk, bv, Qf, Kf, Vt);
    attn_kernel<<<512, 512, 0, stream>>>(Qf, Kf, Vt, out);
}